// Round 8
// baseline (3141.622 us; speedup 1.0000x reference)
//
#include <hip/hip_runtime.h>
#include <math.h>
#include <stddef.h>
#include <stdint.h>

// ---------------------------------------------------------------------------
// ReNet: patches -> vert bidir LSTM -> horiz bidir LSTM -> dense+relu
// B=64, I=J=32, D=12, HID=256, FC=1024.
// Round 8: pin sweep to 2 waves/EU (256-VGPR budget) so the zx prefetch /
// R-fragment double-buffer can actually stay in registers; zx prefetched one
// full pass ahead via statically-selected zrA/zrB.
// ---------------------------------------------------------------------------

namespace {

typedef __bf16 bf16x8 __attribute__((ext_vector_type(8)));
typedef float f32x4 __attribute__((ext_vector_type(4)));
typedef unsigned int u32x4 __attribute__((ext_vector_type(4)));
typedef __attribute__((address_space(1))) unsigned int as1_uint;
typedef __attribute__((address_space(3))) unsigned int as3_uint;

__device__ __forceinline__ float bf2f(ushort u) {
  return __builtin_bit_cast(float, (unsigned int)u << 16);
}
__device__ __forceinline__ ushort f2bf(float f) {
  unsigned int u = __builtin_bit_cast(unsigned int, f);
  u += 0x7fffu + ((u >> 16) & 1u);
  return (ushort)(u >> 16);
}
__device__ __forceinline__ float sigm(float x) {
  return __fdividef(1.f, 1.f + __expf(-x));
}
__device__ __forceinline__ float tanh_(float x) {
  return 2.f * sigm(2.f * x) - 1.f;
}
__device__ __forceinline__ f32x4 mfma16(bf16x8 a, bf16x8 b, f32x4 c) {
  return __builtin_amdgcn_mfma_f32_16x16x32_bf16(a, b, c, 0, 0, 0);
}
__device__ __forceinline__ void load_lds16(const void* g, void* l) {
  __builtin_amdgcn_global_load_lds((const as1_uint*)g, (as3_uint*)l, 16, 0, 0);
}

// --------------------------------------------------------------------------
// transpose f32 [K][1024] -> bf16 [1024][K]  (for gemm B operands)
__global__ __launch_bounds__(256) void transpose_bf16(
    const float* __restrict__ in, ushort* __restrict__ out, int K) {
  const int idx = blockIdx.x * 256 + threadIdx.x;
  if (idx >= (K << 10)) return;
  const int n = idx / K, k = idx - n * K;
  out[idx] = f2bf(in[k * 1024 + n]);
}

// --------------------------------------------------------------------------
// Repack recurrent weights r [256][1024] f32 into MFMA B-fragment-major bf16:
// out[tile=gc/16 (64)][kc (8)][lane (64)][8], elem j = r[kc*32+(lane>>4)*8+j]
//                                                      [tile*16 + (lane&15)]
__global__ __launch_bounds__(256) void rfrag_kernel(
    const float* __restrict__ r, ushort* __restrict__ out) {
  const int id = blockIdx.x * 256 + threadIdx.x;  // 32768 ids
  const int lane = id & 63, kc = (id >> 6) & 7, tile = id >> 9;
  const int kbase = (kc << 5) + ((lane >> 4) << 3);
  const int col = (tile << 4) + (lane & 15);
  ushort tmp[8];
#pragma unroll
  for (int j = 0; j < 8; ++j) tmp[j] = f2bf(r[(size_t)(kbase + j) * 1024 + col]);
  *(uint4*)&out[(size_t)id << 3] = *(const uint4*)tmp;
}

// --------------------------------------------------------------------------
// Vertical input projection into pair-interleaved Z:
// Zu (uint view) [dir][n2=1024][seq=32][col=1024], uint = (bf16 row even,
// bf16 row odd). Rows n = b*32+j, seq = i. Block = (jpair, b, dir).
__global__ __launch_bounds__(256) void zxv2_kernel(
    const float* __restrict__ x, const float* __restrict__ k0_,
    const float* __restrict__ b0_, const float* __restrict__ k1_,
    const float* __restrict__ b1_, unsigned int* __restrict__ Zu) {
  const int tid = threadIdx.x;
  const int jp = blockIdx.x, b = blockIdx.y, dir = blockIdx.z;
  const int j0 = jp << 1;
  const float* kw_ = dir ? k1_ : k0_;
  const float* bw_ = dir ? b1_ : b0_;
  __shared__ float kw[12][1024];
  __shared__ float ps[2][32][12];
  for (int e = tid; e < 12 * 1024; e += 256) kw[e >> 10][e & 1023] = kw_[e];
  for (int e = tid; e < 2 * 32 * 12; e += 256) {
    const int jj = e / 384, rest = e - jj * 384;
    const int i = rest / 12, q = rest - i * 12;
    const int pr = q / 6, rem = q - pr * 6;
    ps[jj][i][q] = x[((size_t)((b * 64 + i * 2 + pr) * 64) + (j0 + jj) * 2 + rem / 3) * 3 + rem % 3];
  }
  __syncthreads();
  const int col = tid << 2;
  float4 kr[12];
#pragma unroll
  for (int q = 0; q < 12; ++q) kr[q] = *(const float4*)&kw[q][col];
  const float4 bias4 = *(const float4*)&bw_[col];
  const int n2 = b * 16 + jp;
  unsigned int* zb = Zu + ((size_t)(dir * 1024 + n2) << 15) + col;
  for (int i = 0; i < 32; ++i) {
    float4 a0 = bias4, a1 = bias4;
#pragma unroll
    for (int q = 0; q < 12; ++q) {
      const float p0 = ps[0][i][q], p1 = ps[1][i][q];
      a0.x += p0 * kr[q].x; a0.y += p0 * kr[q].y;
      a0.z += p0 * kr[q].z; a0.w += p0 * kr[q].w;
      a1.x += p1 * kr[q].x; a1.y += p1 * kr[q].y;
      a1.z += p1 * kr[q].z; a1.w += p1 * kr[q].w;
    }
    uint4 o;
    o.x = (unsigned int)f2bf(a0.x) | ((unsigned int)f2bf(a1.x) << 16);
    o.y = (unsigned int)f2bf(a0.y) | ((unsigned int)f2bf(a1.y) << 16);
    o.z = (unsigned int)f2bf(a0.z) | ((unsigned int)f2bf(a1.z) << 16);
    o.w = (unsigned int)f2bf(a0.w) | ((unsigned int)f2bf(a1.w) << 16);
    *(uint4*)(zb + ((size_t)i << 10)) = o;
  }
}

// --------------------------------------------------------------------------
// Self-contained bidirectional LSTM sweep, round 8.
// Grid (32 rowblk, 2 dir) = 64 blocks, 512 threads (8 waves), PINNED to
// 2 waves/EU -> 256 VGPR budget (round 7's 128-VGPR default serialized all
// loads). Block owns rows [rb*64,+64) x ALL 256 h; wave w owns h-cols
// [w*32,+32). Per step: two passes q=0,1 (16-col halves). zx for pass s+1 is
// issued at the start of pass s (zrA/zrB, statically selected). R fragments
// double-buffered. h double-buffered in LDS, one barrier/step.
__global__ __attribute__((amdgpu_waves_per_eu(2, 2))) __launch_bounds__(512)
void lstm_sweep4(
    const unsigned int* __restrict__ Zu, const uint4* __restrict__ rF,
    ushort* __restrict__ outbuf, int vert) {
  const int tid = threadIdx.x;
  const int lane = tid & 63, w = tid >> 6;
  const int l16 = lane & 15, kg = lane >> 4;
  const int rb = blockIdx.x, dir = (int)blockIdx.y;
  const int rowbase = rb << 6;

  __shared__ ushort hbuf[2][64 * 256];  // 2 x 32 KB, 16B-chunk XOR swizzle

  const uint4* rFd = rF + (size_t)dir * 32768;  // [64 tiles][8 kc][64 lanes]
  const unsigned int* zbase = Zu + (((size_t)dir * 1024 + (rb << 5)) << 15);

  float cst[2][4][4];  // [q][mt][r]
#pragma unroll
  for (int q = 0; q < 2; ++q)
#pragma unroll
    for (int mt = 0; mt < 4; ++mt)
#pragma unroll
      for (int r = 0; r < 4; ++r) cst[q][mt][r] = 0.f;

  unsigned int zrA[4][4][2], zrB[4][4][2];

  // prologue: zx for (t=0, q=0) -> zrA
  {
    const int seq0 = dir ? 31 : 0;
#pragma unroll
    for (int mt = 0; mt < 4; ++mt)
#pragma unroll
      for (int g = 0; g < 4; ++g)
#pragma unroll
        for (int p = 0; p < 2; ++p) {
          const int col = (g << 8) + (w << 5) + l16;
          const int n2l = (mt << 3) + (kg << 1) + p;
          zrA[mt][g][p] = zbase[(((size_t)(n2l << 5) + seq0) << 10) + col];
        }
  }

  for (int t = 0; t < 32; ++t) {
    const int seq = dir ? (31 - t) : t;
    const ushort* hprev = hbuf[(t + 1) & 1];  // h(t-1)
    ushort* hnext = hbuf[t & 1];              // h(t)

#pragma unroll
    for (int q = 0; q < 2; ++q) {
      unsigned int (&zc)[4][4][2] = q ? zrB : zrA;  // consumed this pass
      unsigned int (&zn)[4][4][2] = q ? zrA : zrB;  // issued for next pass

      // ---- issue next-pass zx loads (full pass of slack) ----
      {
        const int tn = q ? ((t + 1) & 31) : t;
        const int seqn = dir ? (31 - tn) : tn;
        const int qn = q ^ 1;
#pragma unroll
        for (int mt = 0; mt < 4; ++mt)
#pragma unroll
          for (int g = 0; g < 4; ++g)
#pragma unroll
            for (int p = 0; p < 2; ++p) {
              const int col = (g << 8) + (w << 5) + (qn << 4) + l16;
              const int n2l = (mt << 3) + (kg << 1) + p;
              zn[mt][g][p] = zbase[(((size_t)(n2l << 5) + seqn) << 10) + col];
            }
      }

      f32x4 acc[4][4];  // [mt][gate]
#pragma unroll
      for (int mt = 0; mt < 4; ++mt)
#pragma unroll
        for (int g = 0; g < 4; ++g) acc[mt][g] = (f32x4){0.f, 0.f, 0.f, 0.f};

      if (t) {
        uint4 bfr[2][4];
#pragma unroll
        for (int g = 0; g < 4; ++g)
          bfr[0][g] = rFd[(size_t)(((g << 4) + (w << 1) + q) << 3) * 64 + lane];
#pragma unroll
        for (int kc = 0; kc < 8; ++kc) {
          const int cur = kc & 1;
          if (kc < 7) {
#pragma unroll
            for (int g = 0; g < 4; ++g)
              bfr[cur ^ 1][g] =
                  rFd[((size_t)(((g << 4) + (w << 1) + q) << 3) + kc + 1) * 64 +
                      lane];
          }
          uint4 a[4];
#pragma unroll
          for (int mt = 0; mt < 4; ++mt) {
            const int row = (mt << 4) + l16;
            const int c4 = (kc << 2) + kg;
            a[mt] = *(const uint4*)((const char*)hprev + row * 512 +
                                    ((c4 ^ (row & 7)) << 4));
          }
#pragma unroll
          for (int mt = 0; mt < 4; ++mt)
#pragma unroll
            for (int g = 0; g < 4; ++g)
              acc[mt][g] = mfma16(__builtin_bit_cast(bf16x8, a[mt]),
                                  __builtin_bit_cast(bf16x8, bfr[cur][g]),
                                  acc[mt][g]);
        }
      }

      // ---- epilogue: z = acc + zx ; c,h update ; stores ----
      const int col = (w << 5) + (q << 4) + l16;
#pragma unroll
      for (int mt = 0; mt < 4; ++mt) {
#pragma unroll
        for (int r = 0; r < 4; ++r) {
          const int sh = (r & 1) << 4;
          const float zi = acc[mt][0][r] + bf2f((ushort)(zc[mt][0][r >> 1] >> sh));
          const float zf = acc[mt][1][r] + bf2f((ushort)(zc[mt][1][r >> 1] >> sh));
          const float zg = acc[mt][2][r] + bf2f((ushort)(zc[mt][2][r >> 1] >> sh));
          const float zo = acc[mt][3][r] + bf2f((ushort)(zc[mt][3][r >> 1] >> sh));
          const float cn = sigm(zf) * cst[q][mt][r] + sigm(zi) * tanh_(zg);
          cst[q][mt][r] = cn;
          const float hv = sigm(zo) * tanh_(cn);
          const ushort h16 = f2bf(hv);
          const int row = (mt << 4) + (kg << 2) + r;
          *(ushort*)((char*)hnext + row * 512 +
                     (((col >> 3) ^ (row & 7)) << 4) + ((col & 7) << 1)) = h16;
          const int n = rowbase + row, b = n >> 5, sp = n & 31;
          const int X = vert ? seq : sp;
          const int Y = vert ? sp : seq;
          outbuf[(((size_t)(b * 32 + X) * 32 + Y) << 9) + (dir << 8) + col] = h16;
        }
      }
    }
    __syncthreads();  // h(t) complete; all h(t-1) reads done
  }
}

// --------------------------------------------------------------------------
// C = A[M][512] @ BT[1024][512]^T + bias. 128x128 tile, BK=64,
// global_load_lds + XOR swizzle, XCD-aware remap, LDS-staged epilogue.
// EPI 0: pair-interleaved Z store (uint = bf16 row-even | row-odd<<16).
// EPI 1: relu f32 store.
template <int EPI>
__global__ __launch_bounds__(256) void gemm_bt(
    const ushort* __restrict__ A, const ushort* __restrict__ BT,
    const float* __restrict__ bias, void* __restrict__ Cv) {
  const int tid = threadIdx.x;
  const int lane = tid & 63, wid = tid >> 6;
  const int l16 = lane & 15, kg = lane >> 4;
  const int wr = wid >> 1, wc = wid & 1;
  const int bid = blockIdx.x;
  const int xcd = bid & 7, lid = bid >> 3;
  const int m0 = ((xcd << 6) + (lid >> 3)) << 7;
  const int n0 = (lid & 7) << 7;

  union SM {
    struct { uint4 A[128][8]; uint4 B[128][8]; } k;
    ushort eh[64][136];
    float ef[64][132];
  };
  __shared__ SM sm;

  f32x4 acc[4][4];
#pragma unroll
  for (int mt = 0; mt < 4; ++mt)
#pragma unroll
    for (int nt = 0; nt < 4; ++nt) acc[mt][nt] = (f32x4){0.f, 0.f, 0.f, 0.f};

  for (int k0 = 0; k0 < 512; k0 += 64) {
#pragma unroll
    for (int c = 0; c < 4; ++c) {
      const int cid = (wid << 8) + (c << 6) + lane;
      const int row = cid >> 3, ch = cid & 7;
      const int sch = ch ^ (row & 7);
      load_lds16(A + (size_t)(m0 + row) * 512 + k0 + (sch << 3),
                 (uint4*)sm.k.A + (cid - lane));
      load_lds16(BT + (size_t)(n0 + row) * 512 + k0 + (sch << 3),
                 (uint4*)sm.k.B + (cid - lane));
    }
    __syncthreads();
#pragma unroll
    for (int kk = 0; kk < 2; ++kk) {
      const int q = (kk << 2) + kg;
      bf16x8 a[4], b[4];
#pragma unroll
      for (int mt = 0; mt < 4; ++mt) {
        const int rr = (wr << 6) + (mt << 4) + l16;
        a[mt] = __builtin_bit_cast(bf16x8, sm.k.A[rr][q ^ (rr & 7)]);
      }
#pragma unroll
      for (int nt = 0; nt < 4; ++nt) {
        const int rr = (wc << 6) + (nt << 4) + l16;
        b[nt] = __builtin_bit_cast(bf16x8, sm.k.B[rr][q ^ (rr & 7)]);
      }
#pragma unroll
      for (int mt = 0; mt < 4; ++mt)
#pragma unroll
        for (int nt = 0; nt < 4; ++nt)
          acc[mt][nt] = mfma16(a[mt], b[nt], acc[mt][nt]);
    }
    __syncthreads();
  }

  float bn[4];
#pragma unroll
  for (int nt = 0; nt < 4; ++nt)
    bn[nt] = bias[n0 + (wc << 6) + (nt << 4) + l16];

#pragma unroll
  for (int h = 0; h < 2; ++h) {
    __syncthreads();
    if (wr == h) {
#pragma unroll
      for (int nt = 0; nt < 4; ++nt) {
        const int col = (wc << 6) + (nt << 4) + l16;
#pragma unroll
        for (int mt = 0; mt < 4; ++mt) {
#pragma unroll
          for (int r = 0; r < 4; ++r) {
            const int rowl = (mt << 4) + (kg << 2) + r;
            const float v = acc[mt][nt][r] + bn[nt];
            if (EPI == 0)
              sm.eh[rowl][col] = f2bf(v);
            else
              sm.ef[rowl][col] = fmaxf(v, 0.f);
          }
        }
      }
    }
    __syncthreads();
    if (EPI == 0) {
      // rows of this half = i-pair {2h, 2h+1} x 32 seq (m = n*32 + seq)
      unsigned int* out = (unsigned int*)Cv;
      const int n2 = (m0 >> 6) + h;
#pragma unroll
      for (int it = 0; it < 16; ++it) {
        const int e = tid + (it << 8);  // 0..4095
        const int seq = e >> 7, col = e & 127;
        const unsigned int v0 = sm.eh[seq][col];
        const unsigned int v1 = sm.eh[32 + seq][col];
        out[((size_t)(n2 * 32 + seq) << 10) + n0 + col] = v0 | (v1 << 16);
      }
    } else {
      float* out = (float*)Cv;
#pragma unroll
      for (int q = 0; q < 8; ++q) {
        const int c = tid + (q << 8);
        const int row = c >> 5, co = (c & 31) << 2;
        const f32x4 v = *(const f32x4*)&sm.ef[row][co];
        __builtin_nontemporal_store(
            v, (f32x4*)(out + (size_t)(m0 + (h << 6) + row) * 1024 + n0 + co));
      }
    }
  }
}

}  // namespace

extern "C" void kernel_launch(void* const* d_in, const int* in_sizes, int n_in,
                              void* d_out, int out_size, void* d_ws, size_t ws_size,
                              hipStream_t stream) {
  (void)in_sizes; (void)n_in; (void)out_size; (void)ws_size;
  const float* x    = (const float*)d_in[0];
  const float* k_ud = (const float*)d_in[1];
  const float* r_ud = (const float*)d_in[2];
  const float* b_ud = (const float*)d_in[3];
  const float* k_du = (const float*)d_in[4];
  const float* r_du = (const float*)d_in[5];
  const float* b_du = (const float*)d_in[6];
  const float* k_lr = (const float*)d_in[7];
  const float* r_lr = (const float*)d_in[8];
  const float* b_lr = (const float*)d_in[9];
  const float* k_rl = (const float*)d_in[10];
  const float* r_rl = (const float*)d_in[11];
  const float* b_rl = (const float*)d_in[12];
  const float* Wd   = (const float*)d_in[13];
  const float* bd   = (const float*)d_in[14];

  ushort* W    = (ushort*)d_ws;
  ushort* Z    = W;                      // [2][1024 n2][32][1024][2]  134217728
  ushort* vbuf = Z + 134217728;          // [64][32][32][512]           33554432
  ushort* rF   = vbuf + 33554432;        // [4][64][8][64][8]            1048576
  ushort* kTh  = rF + 1048576;           // [2][1024][512]               1048576
  ushort* WdT  = kTh + 1048576;          // [1024][512]                   524288

  // ---- weight prep ----
  rfrag_kernel<<<128, 256, 0, stream>>>(r_ud, rF);
  rfrag_kernel<<<128, 256, 0, stream>>>(r_du, rF + 262144);
  rfrag_kernel<<<128, 256, 0, stream>>>(r_lr, rF + 524288);
  rfrag_kernel<<<128, 256, 0, stream>>>(r_rl, rF + 786432);
  transpose_bf16<<<2048, 256, 0, stream>>>(k_lr, kTh, 512);
  transpose_bf16<<<2048, 256, 0, stream>>>(k_rl, kTh + 524288, 512);
  transpose_bf16<<<2048, 256, 0, stream>>>(Wd, WdT, 512);

  // ---- vertical input projection (K=12), pair-interleaved Z ----
  zxv2_kernel<<<dim3(16, 64, 2), 256, 0, stream>>>(x, k_ud, b_ud, k_du, b_du,
                                                   (unsigned int*)Z);

  // ---- vertical sweep ----
  lstm_sweep4<<<dim3(32, 2), 512, 0, stream>>>((const unsigned int*)Z,
                                               (const uint4*)rF, vbuf, 1);

  // ---- horizontal input projection: Z = v @ k + b (per dir) ----
  gemm_bt<0><<<4096, 256, 0, stream>>>(vbuf, kTh, b_lr, (void*)Z);
  gemm_bt<0><<<4096, 256, 0, stream>>>(vbuf, kTh + 524288, b_rl,
                                       (void*)(Z + 67108864));

  // ---- horizontal sweep (writes hfin over vbuf; reads only Z) ----
  lstm_sweep4<<<dim3(32, 2), 512, 0, stream>>>(
      (const unsigned int*)Z, (const uint4*)(rF + 524288), vbuf, 0);

  // ---- dense + relu ----
  gemm_bt<1><<<4096, 256, 0, stream>>>(vbuf, WdT, bd, d_out);
}

// Round 9
// 1258.137 us; speedup vs baseline: 2.4970x; 2.4970x over previous
//
#include <hip/hip_runtime.h>
#include <math.h>
#include <stddef.h>
#include <stdint.h>

// ---------------------------------------------------------------------------
// ReNet: patches -> vert bidir LSTM -> horiz bidir LSTM -> dense+relu
// B=64, I=J=32, D=12, HID=256, FC=1024.
// Round 9: 32-row blocks (grid 128 -> 2x CUs busy) shrink the per-pass
// register set to ~124 so it genuinely fits the 128-VGPR budget: acc[2][4],
// B-fragment kc+1 ring, zx regs, cst regs. No occupancy attributes.
// ---------------------------------------------------------------------------

namespace {

typedef __bf16 bf16x8 __attribute__((ext_vector_type(8)));
typedef float f32x4 __attribute__((ext_vector_type(4)));
typedef unsigned int u32x4 __attribute__((ext_vector_type(4)));
typedef __attribute__((address_space(1))) unsigned int as1_uint;
typedef __attribute__((address_space(3))) unsigned int as3_uint;

__device__ __forceinline__ float bf2f(ushort u) {
  return __builtin_bit_cast(float, (unsigned int)u << 16);
}
__device__ __forceinline__ ushort f2bf(float f) {
  unsigned int u = __builtin_bit_cast(unsigned int, f);
  u += 0x7fffu + ((u >> 16) & 1u);
  return (ushort)(u >> 16);
}
__device__ __forceinline__ float sigm(float x) {
  return __fdividef(1.f, 1.f + __expf(-x));
}
__device__ __forceinline__ float tanh_(float x) {
  return 2.f * sigm(2.f * x) - 1.f;
}
__device__ __forceinline__ f32x4 mfma16(bf16x8 a, bf16x8 b, f32x4 c) {
  return __builtin_amdgcn_mfma_f32_16x16x32_bf16(a, b, c, 0, 0, 0);
}
__device__ __forceinline__ void load_lds16(const void* g, void* l) {
  __builtin_amdgcn_global_load_lds((const as1_uint*)g, (as3_uint*)l, 16, 0, 0);
}

// --------------------------------------------------------------------------
// transpose f32 [K][1024] -> bf16 [1024][K]  (for gemm B operands)
__global__ __launch_bounds__(256) void transpose_bf16(
    const float* __restrict__ in, ushort* __restrict__ out, int K) {
  const int idx = blockIdx.x * 256 + threadIdx.x;
  if (idx >= (K << 10)) return;
  const int n = idx / K, k = idx - n * K;
  out[idx] = f2bf(in[k * 1024 + n]);
}

// --------------------------------------------------------------------------
// Repack recurrent weights r [256][1024] f32 into MFMA B-fragment-major bf16:
// out[tile=gc/16 (64)][kc (8)][lane (64)][8], elem j = r[kc*32+(lane>>4)*8+j]
//                                                      [tile*16 + (lane&15)]
__global__ __launch_bounds__(256) void rfrag_kernel(
    const float* __restrict__ r, ushort* __restrict__ out) {
  const int id = blockIdx.x * 256 + threadIdx.x;  // 32768 ids
  const int lane = id & 63, kc = (id >> 6) & 7, tile = id >> 9;
  const int kbase = (kc << 5) + ((lane >> 4) << 3);
  const int col = (tile << 4) + (lane & 15);
  ushort tmp[8];
#pragma unroll
  for (int j = 0; j < 8; ++j) tmp[j] = f2bf(r[(size_t)(kbase + j) * 1024 + col]);
  *(uint4*)&out[(size_t)id << 3] = *(const uint4*)tmp;
}

// --------------------------------------------------------------------------
// Vertical input projection into pair-interleaved Z:
// Zu (uint view) [dir][n2=1024][seq=32][col=1024], uint = (bf16 row even,
// bf16 row odd). Rows n = b*32+j, seq = i. Block = (jpair, b, dir).
__global__ __launch_bounds__(256) void zxv2_kernel(
    const float* __restrict__ x, const float* __restrict__ k0_,
    const float* __restrict__ b0_, const float* __restrict__ k1_,
    const float* __restrict__ b1_, unsigned int* __restrict__ Zu) {
  const int tid = threadIdx.x;
  const int jp = blockIdx.x, b = blockIdx.y, dir = blockIdx.z;
  const int j0 = jp << 1;
  const float* kw_ = dir ? k1_ : k0_;
  const float* bw_ = dir ? b1_ : b0_;
  __shared__ float kw[12][1024];
  __shared__ float ps[2][32][12];
  for (int e = tid; e < 12 * 1024; e += 256) kw[e >> 10][e & 1023] = kw_[e];
  for (int e = tid; e < 2 * 32 * 12; e += 256) {
    const int jj = e / 384, rest = e - jj * 384;
    const int i = rest / 12, q = rest - i * 12;
    const int pr = q / 6, rem = q - pr * 6;
    ps[jj][i][q] = x[((size_t)((b * 64 + i * 2 + pr) * 64) + (j0 + jj) * 2 + rem / 3) * 3 + rem % 3];
  }
  __syncthreads();
  const int col = tid << 2;
  float4 kr[12];
#pragma unroll
  for (int q = 0; q < 12; ++q) kr[q] = *(const float4*)&kw[q][col];
  const float4 bias4 = *(const float4*)&bw_[col];
  const int n2 = b * 16 + jp;
  unsigned int* zb = Zu + ((size_t)(dir * 1024 + n2) << 15) + col;
  for (int i = 0; i < 32; ++i) {
    float4 a0 = bias4, a1 = bias4;
#pragma unroll
    for (int q = 0; q < 12; ++q) {
      const float p0 = ps[0][i][q], p1 = ps[1][i][q];
      a0.x += p0 * kr[q].x; a0.y += p0 * kr[q].y;
      a0.z += p0 * kr[q].z; a0.w += p0 * kr[q].w;
      a1.x += p1 * kr[q].x; a1.y += p1 * kr[q].y;
      a1.z += p1 * kr[q].z; a1.w += p1 * kr[q].w;
    }
    uint4 o;
    o.x = (unsigned int)f2bf(a0.x) | ((unsigned int)f2bf(a1.x) << 16);
    o.y = (unsigned int)f2bf(a0.y) | ((unsigned int)f2bf(a1.y) << 16);
    o.z = (unsigned int)f2bf(a0.z) | ((unsigned int)f2bf(a1.z) << 16);
    o.w = (unsigned int)f2bf(a0.w) | ((unsigned int)f2bf(a1.w) << 16);
    *(uint4*)(zb + ((size_t)i << 10)) = o;
  }
}

// --------------------------------------------------------------------------
// Self-contained bidirectional LSTM sweep, round 9.
// Grid (64 rowblk, 2 dir) = 128 blocks, 512 threads (8 waves).
// Block owns rows [rb*32,+32) x ALL 256 h; wave w owns h-cols [w*32,+32),
// two passes q=0,1 (16 cols x 4 gates each). Per-pass register budget ~124:
// acc[2][4]=32, bfr ring[2][4]=32, a[2]=8, zr=16, cst=16. h double-buffered
// in LDS (2x16KB), one barrier/step. R streamed fragment-major from L2.
__global__ __launch_bounds__(512) void lstm_sweep5(
    const unsigned int* __restrict__ Zu, const uint4* __restrict__ rF,
    ushort* __restrict__ outbuf, int vert) {
  const int tid = threadIdx.x;
  const int lane = tid & 63, w = tid >> 6;
  const int l16 = lane & 15, kg = lane >> 4;
  const int rb = blockIdx.x, dir = (int)blockIdx.y;
  const int rowbase = rb << 5;

  __shared__ ushort hbuf[2][32 * 256];  // 2 x 16 KB, 16B-chunk XOR swizzle

  const uint4* rFd = rF + (size_t)dir * 32768;  // [64 tiles][8 kc][64 lanes]
  const unsigned int* zbase = Zu + (((size_t)dir * 1024 + (rb << 4)) << 15);

  float cst[2][2][4];  // [q][mt][r]
#pragma unroll
  for (int q = 0; q < 2; ++q)
#pragma unroll
    for (int mt = 0; mt < 2; ++mt)
#pragma unroll
      for (int r = 0; r < 4; ++r) cst[q][mt][r] = 0.f;

  for (int t = 0; t < 32; ++t) {
    const int seq = dir ? (31 - t) : t;
    const ushort* hprev = hbuf[(t + 1) & 1];  // h(t-1)
    ushort* hnext = hbuf[t & 1];              // h(t)

#pragma unroll
    for (int q = 0; q < 2; ++q) {
      // ---- issue zx loads; consumed after the MFMA chain (latency hidden)
      unsigned int zr[2][4][2];  // [mt][gate][rowpair]
#pragma unroll
      for (int mt = 0; mt < 2; ++mt)
#pragma unroll
        for (int g = 0; g < 4; ++g)
#pragma unroll
          for (int p = 0; p < 2; ++p) {
            const int col = (g << 8) + (w << 5) + (q << 4) + l16;
            const int n2l = (mt << 3) + (kg << 1) + p;
            zr[mt][g][p] = zbase[(((size_t)(n2l << 5) + seq) << 10) + col];
          }

      f32x4 acc[2][4];  // [mt][gate]
#pragma unroll
      for (int mt = 0; mt < 2; ++mt)
#pragma unroll
        for (int g = 0; g < 4; ++g) acc[mt][g] = (f32x4){0.f, 0.f, 0.f, 0.f};

      if (t) {
        uint4 bfr[2][4];  // kc ring
#pragma unroll
        for (int g = 0; g < 4; ++g)
          bfr[0][g] = rFd[(size_t)(((g << 4) + (w << 1) + q) << 3) * 64 + lane];
#pragma unroll
        for (int kc = 0; kc < 8; ++kc) {
          const int cur = kc & 1;
          if (kc < 7) {
#pragma unroll
            for (int g = 0; g < 4; ++g)
              bfr[cur ^ 1][g] =
                  rFd[((size_t)(((g << 4) + (w << 1) + q) << 3) + kc + 1) * 64 +
                      lane];
          }
          uint4 a[2];
#pragma unroll
          for (int mt = 0; mt < 2; ++mt) {
            const int row = (mt << 4) + l16;
            const int c4 = (kc << 2) + kg;
            a[mt] = *(const uint4*)((const char*)hprev + row * 512 +
                                    ((c4 ^ (row & 7)) << 4));
          }
#pragma unroll
          for (int mt = 0; mt < 2; ++mt)
#pragma unroll
            for (int g = 0; g < 4; ++g)
              acc[mt][g] = mfma16(__builtin_bit_cast(bf16x8, a[mt]),
                                  __builtin_bit_cast(bf16x8, bfr[cur][g]),
                                  acc[mt][g]);
        }
      }

      // ---- epilogue: z = acc + zx ; c,h update ; stores ----
      const int col = (w << 5) + (q << 4) + l16;
#pragma unroll
      for (int mt = 0; mt < 2; ++mt) {
#pragma unroll
        for (int r = 0; r < 4; ++r) {
          const int sh = (r & 1) << 4;
          const float zi = acc[mt][0][r] + bf2f((ushort)(zr[mt][0][r >> 1] >> sh));
          const float zf = acc[mt][1][r] + bf2f((ushort)(zr[mt][1][r >> 1] >> sh));
          const float zg = acc[mt][2][r] + bf2f((ushort)(zr[mt][2][r >> 1] >> sh));
          const float zo = acc[mt][3][r] + bf2f((ushort)(zr[mt][3][r >> 1] >> sh));
          const float cn = sigm(zf) * cst[q][mt][r] + sigm(zi) * tanh_(zg);
          cst[q][mt][r] = cn;
          const float hv = sigm(zo) * tanh_(cn);
          const ushort h16 = f2bf(hv);
          const int row = (mt << 4) + (kg << 2) + r;
          *(ushort*)((char*)hnext + row * 512 +
                     (((col >> 3) ^ (row & 7)) << 4) + ((col & 7) << 1)) = h16;
          const int n = rowbase + row, b = n >> 5, sp = n & 31;
          const int X = vert ? seq : sp;
          const int Y = vert ? sp : seq;
          outbuf[(((size_t)(b * 32 + X) * 32 + Y) << 9) + (dir << 8) + col] = h16;
        }
      }
    }
    __syncthreads();  // h(t) complete; all h(t-1) reads done
  }
}

// --------------------------------------------------------------------------
// C = A[M][512] @ BT[1024][512]^T + bias. 128x128 tile, BK=64,
// global_load_lds + XOR swizzle, XCD-aware remap, LDS-staged epilogue.
// EPI 0: pair-interleaved Z store (uint = bf16 row-even | row-odd<<16).
// EPI 1: relu f32 store.
template <int EPI>
__global__ __launch_bounds__(256) void gemm_bt(
    const ushort* __restrict__ A, const ushort* __restrict__ BT,
    const float* __restrict__ bias, void* __restrict__ Cv) {
  const int tid = threadIdx.x;
  const int lane = tid & 63, wid = tid >> 6;
  const int l16 = lane & 15, kg = lane >> 4;
  const int wr = wid >> 1, wc = wid & 1;
  const int bid = blockIdx.x;
  const int xcd = bid & 7, lid = bid >> 3;
  const int m0 = ((xcd << 6) + (lid >> 3)) << 7;
  const int n0 = (lid & 7) << 7;

  union SM {
    struct { uint4 A[128][8]; uint4 B[128][8]; } k;
    ushort eh[64][136];
    float ef[64][132];
  };
  __shared__ SM sm;

  f32x4 acc[4][4];
#pragma unroll
  for (int mt = 0; mt < 4; ++mt)
#pragma unroll
    for (int nt = 0; nt < 4; ++nt) acc[mt][nt] = (f32x4){0.f, 0.f, 0.f, 0.f};

  for (int k0 = 0; k0 < 512; k0 += 64) {
#pragma unroll
    for (int c = 0; c < 4; ++c) {
      const int cid = (wid << 8) + (c << 6) + lane;
      const int row = cid >> 3, ch = cid & 7;
      const int sch = ch ^ (row & 7);
      load_lds16(A + (size_t)(m0 + row) * 512 + k0 + (sch << 3),
                 (uint4*)sm.k.A + (cid - lane));
      load_lds16(BT + (size_t)(n0 + row) * 512 + k0 + (sch << 3),
                 (uint4*)sm.k.B + (cid - lane));
    }
    __syncthreads();
#pragma unroll
    for (int kk = 0; kk < 2; ++kk) {
      const int q = (kk << 2) + kg;
      bf16x8 a[4], b[4];
#pragma unroll
      for (int mt = 0; mt < 4; ++mt) {
        const int rr = (wr << 6) + (mt << 4) + l16;
        a[mt] = __builtin_bit_cast(bf16x8, sm.k.A[rr][q ^ (rr & 7)]);
      }
#pragma unroll
      for (int nt = 0; nt < 4; ++nt) {
        const int rr = (wc << 6) + (nt << 4) + l16;
        b[nt] = __builtin_bit_cast(bf16x8, sm.k.B[rr][q ^ (rr & 7)]);
      }
#pragma unroll
      for (int mt = 0; mt < 4; ++mt)
#pragma unroll
        for (int nt = 0; nt < 4; ++nt)
          acc[mt][nt] = mfma16(a[mt], b[nt], acc[mt][nt]);
    }
    __syncthreads();
  }

  float bn[4];
#pragma unroll
  for (int nt = 0; nt < 4; ++nt)
    bn[nt] = bias[n0 + (wc << 6) + (nt << 4) + l16];

#pragma unroll
  for (int h = 0; h < 2; ++h) {
    __syncthreads();
    if (wr == h) {
#pragma unroll
      for (int nt = 0; nt < 4; ++nt) {
        const int col = (wc << 6) + (nt << 4) + l16;
#pragma unroll
        for (int mt = 0; mt < 4; ++mt) {
#pragma unroll
          for (int r = 0; r < 4; ++r) {
            const int rowl = (mt << 4) + (kg << 2) + r;
            const float v = acc[mt][nt][r] + bn[nt];
            if (EPI == 0)
              sm.eh[rowl][col] = f2bf(v);
            else
              sm.ef[rowl][col] = fmaxf(v, 0.f);
          }
        }
      }
    }
    __syncthreads();
    if (EPI == 0) {
      // rows of this half = i-pair {2h, 2h+1} x 32 seq (m = n*32 + seq)
      unsigned int* out = (unsigned int*)Cv;
      const int n2 = (m0 >> 6) + h;
#pragma unroll
      for (int it = 0; it < 16; ++it) {
        const int e = tid + (it << 8);  // 0..4095
        const int seq = e >> 7, col = e & 127;
        const unsigned int v0 = sm.eh[seq][col];
        const unsigned int v1 = sm.eh[32 + seq][col];
        out[((size_t)(n2 * 32 + seq) << 10) + n0 + col] = v0 | (v1 << 16);
      }
    } else {
      float* out = (float*)Cv;
#pragma unroll
      for (int q = 0; q < 8; ++q) {
        const int c = tid + (q << 8);
        const int row = c >> 5, co = (c & 31) << 2;
        const f32x4 v = *(const f32x4*)&sm.ef[row][co];
        __builtin_nontemporal_store(
            v, (f32x4*)(out + (size_t)(m0 + (h << 6) + row) * 1024 + n0 + co));
      }
    }
  }
}

}  // namespace

extern "C" void kernel_launch(void* const* d_in, const int* in_sizes, int n_in,
                              void* d_out, int out_size, void* d_ws, size_t ws_size,
                              hipStream_t stream) {
  (void)in_sizes; (void)n_in; (void)out_size; (void)ws_size;
  const float* x    = (const float*)d_in[0];
  const float* k_ud = (const float*)d_in[1];
  const float* r_ud = (const float*)d_in[2];
  const float* b_ud = (const float*)d_in[3];
  const float* k_du = (const float*)d_in[4];
  const float* r_du = (const float*)d_in[5];
  const float* b_du = (const float*)d_in[6];
  const float* k_lr = (const float*)d_in[7];
  const float* r_lr = (const float*)d_in[8];
  const float* b_lr = (const float*)d_in[9];
  const float* k_rl = (const float*)d_in[10];
  const float* r_rl = (const float*)d_in[11];
  const float* b_rl = (const float*)d_in[12];
  const float* Wd   = (const float*)d_in[13];
  const float* bd   = (const float*)d_in[14];

  ushort* W    = (ushort*)d_ws;
  ushort* Z    = W;                      // [2][1024 n2][32][1024][2]  134217728
  ushort* vbuf = Z + 134217728;          // [64][32][32][512]           33554432
  ushort* rF   = vbuf + 33554432;        // [4][64][8][64][8]            1048576
  ushort* kTh  = rF + 1048576;           // [2][1024][512]               1048576
  ushort* WdT  = kTh + 1048576;          // [1024][512]                   524288

  // ---- weight prep ----
  rfrag_kernel<<<128, 256, 0, stream>>>(r_ud, rF);
  rfrag_kernel<<<128, 256, 0, stream>>>(r_du, rF + 262144);
  rfrag_kernel<<<128, 256, 0, stream>>>(r_lr, rF + 524288);
  rfrag_kernel<<<128, 256, 0, stream>>>(r_rl, rF + 786432);
  transpose_bf16<<<2048, 256, 0, stream>>>(k_lr, kTh, 512);
  transpose_bf16<<<2048, 256, 0, stream>>>(k_rl, kTh + 524288, 512);
  transpose_bf16<<<2048, 256, 0, stream>>>(Wd, WdT, 512);

  // ---- vertical input projection (K=12), pair-interleaved Z ----
  zxv2_kernel<<<dim3(16, 64, 2), 256, 0, stream>>>(x, k_ud, b_ud, k_du, b_du,
                                                   (unsigned int*)Z);

  // ---- vertical sweep ----
  lstm_sweep5<<<dim3(64, 2), 512, 0, stream>>>((const unsigned int*)Z,
                                               (const uint4*)rF, vbuf, 1);

  // ---- horizontal input projection: Z = v @ k + b (per dir) ----
  gemm_bt<0><<<4096, 256, 0, stream>>>(vbuf, kTh, b_lr, (void*)Z);
  gemm_bt<0><<<4096, 256, 0, stream>>>(vbuf, kTh + 524288, b_rl,
                                       (void*)(Z + 67108864));

  // ---- horizontal sweep (writes hfin over vbuf; reads only Z) ----
  lstm_sweep5<<<dim3(64, 2), 512, 0, stream>>>(
      (const unsigned int*)Z, (const uint4*)(rF + 524288), vbuf, 0);

  // ---- dense + relu ----
  gemm_bt<1><<<4096, 256, 0, stream>>>(vbuf, WdT, bd, d_out);
}

// Round 10
// 1111.356 us; speedup vs baseline: 2.8268x; 1.1321x over previous
//
#include <hip/hip_runtime.h>
#include <math.h>
#include <stddef.h>
#include <stdint.h>

// ---------------------------------------------------------------------------
// ReNet: patches -> vert bidir LSTM -> horiz bidir LSTM -> dense+relu
// B=64, I=J=32, D=12, HID=256, FC=1024.
// Round 10: Z in MFMA-fragment-major layout (4 coalesced uint4 loads/pass,
// gates in components, row-pairs packed); acc init = zx; next-pass zx issued
// after last bfr issue (no vmcnt inversion); out-copy LDS->global overlapped
// at next step start; __launch_bounds__(512,2) for VGPR headroom.
// ---------------------------------------------------------------------------

namespace {

typedef __bf16 bf16x8 __attribute__((ext_vector_type(8)));
typedef float f32x4 __attribute__((ext_vector_type(4)));
typedef __attribute__((address_space(1))) unsigned int as1_uint;
typedef __attribute__((address_space(3))) unsigned int as3_uint;

__device__ __forceinline__ float bf2f(ushort u) {
  return __builtin_bit_cast(float, (unsigned int)u << 16);
}
__device__ __forceinline__ ushort f2bf(float f) {
  unsigned int u = __builtin_bit_cast(unsigned int, f);
  u += 0x7fffu + ((u >> 16) & 1u);
  return (ushort)(u >> 16);
}
__device__ __forceinline__ unsigned int packbf(float a, float b) {
  return (unsigned int)f2bf(a) | ((unsigned int)f2bf(b) << 16);
}
__device__ __forceinline__ float sigm(float x) {
  return __fdividef(1.f, 1.f + __expf(-x));
}
__device__ __forceinline__ float tanh_(float x) {
  return 2.f * sigm(2.f * x) - 1.f;
}
__device__ __forceinline__ f32x4 mfma16(bf16x8 a, bf16x8 b, f32x4 c) {
  return __builtin_amdgcn_mfma_f32_16x16x32_bf16(a, b, c, 0, 0, 0);
}
__device__ __forceinline__ void load_lds16(const void* g, void* l) {
  __builtin_amdgcn_global_load_lds((const as1_uint*)g, (as3_uint*)l, 16, 0, 0);
}

// Zf fragment-major layout, per (dir, rb): 131072 uint4.
// uint4 index = ((seq*2 + q)*4 + chunk)*512 + tidz ; components = gates 0..3.
// uint packs bf16 rows (2*n2l, 2*n2l+1), n2l = (mt<<3)+(kg<<1)+p,
// chunk = mt*2+p, tidz = w*64+kg*16+l16, hcol = w*32+q*16+l16.

// --------------------------------------------------------------------------
// transpose f32 [K][1024] -> bf16 [1024][K]  (for gemm B operands)
__global__ __launch_bounds__(256) void transpose_bf16(
    const float* __restrict__ in, ushort* __restrict__ out, int K) {
  const int idx = blockIdx.x * 256 + threadIdx.x;
  if (idx >= (K << 10)) return;
  const int n = idx / K, k = idx - n * K;
  out[idx] = f2bf(in[k * 1024 + n]);
}

// --------------------------------------------------------------------------
// Repack recurrent weights r [256][1024] f32 into MFMA B-fragment-major bf16
__global__ __launch_bounds__(256) void rfrag_kernel(
    const float* __restrict__ r, ushort* __restrict__ out) {
  const int id = blockIdx.x * 256 + threadIdx.x;  // 32768 ids
  const int lane = id & 63, kc = (id >> 6) & 7, tile = id >> 9;
  const int kbase = (kc << 5) + ((lane >> 4) << 3);
  const int col = (tile << 4) + (lane & 15);
  ushort tmp[8];
#pragma unroll
  for (int j = 0; j < 8; ++j) tmp[j] = f2bf(r[(size_t)(kbase + j) * 1024 + col]);
  *(uint4*)&out[(size_t)id << 3] = *(const uint4*)tmp;
}

// --------------------------------------------------------------------------
// Vertical input projection -> fragment-major Zf. Block (jp, b, dir), 256 thr;
// thread tid = hcol (0..255), computes all 4 gates for rows j0=2jp, j0+1.
__global__ __launch_bounds__(256) void zxv3_kernel(
    const float* __restrict__ x, const float* __restrict__ k0_,
    const float* __restrict__ b0_, const float* __restrict__ k1_,
    const float* __restrict__ b1_, uint4* __restrict__ Zf) {
  const int tid = threadIdx.x;
  const int jp = blockIdx.x, b = blockIdx.y, dir = blockIdx.z;
  const int j0 = jp << 1;
  const float* kw_ = dir ? k1_ : k0_;
  const float* bw_ = dir ? b1_ : b0_;
  __shared__ float ps[2][32][12];
  for (int e = tid; e < 2 * 32 * 12; e += 256) {
    const int jj = e / 384, rest = e - jj * 384;
    const int i = rest / 12, qq = rest - i * 12;
    const int pr = qq / 6, rem = qq - pr * 6;
    ps[jj][i][qq] =
        x[((size_t)((b * 64 + i * 2 + pr) * 64) + (j0 + jj) * 2 + rem / 3) * 3 + rem % 3];
  }
  __syncthreads();
  float kr[12][4], br[4];
#pragma unroll
  for (int qq = 0; qq < 12; ++qq)
#pragma unroll
    for (int g = 0; g < 4; ++g) kr[qq][g] = kw_[qq * 1024 + (g << 8) + tid];
#pragma unroll
  for (int g = 0; g < 4; ++g) br[g] = bw_[(g << 8) + tid];

  const int wv = tid >> 5, qv = (tid >> 4) & 1, l16v = tid & 15;
  const int kgz = (jp >> 1) & 3;
  const int chunk = ((jp >> 3) << 1) + (jp & 1);
  const int tidz = (wv << 6) + (kgz << 4) + l16v;
  uint4* base = Zf + ((size_t)dir * 64 + b) * 131072;

  for (int i = 0; i < 32; ++i) {
    float z0[4], z1[4];
#pragma unroll
    for (int g = 0; g < 4; ++g) { z0[g] = br[g]; z1[g] = br[g]; }
#pragma unroll
    for (int qq = 0; qq < 12; ++qq) {
      const float p0 = ps[0][i][qq], p1 = ps[1][i][qq];
#pragma unroll
      for (int g = 0; g < 4; ++g) {
        z0[g] += p0 * kr[qq][g];
        z1[g] += p1 * kr[qq][g];
      }
    }
    uint4 o;
    o.x = packbf(z0[0], z1[0]);
    o.y = packbf(z0[1], z1[1]);
    o.z = packbf(z0[2], z1[2]);
    o.w = packbf(z0[3], z1[3]);
    base[(size_t)(((i << 1) + qv) * 4 + chunk) * 512 + tidz] = o;
  }
}

// --------------------------------------------------------------------------
// Self-contained bidirectional LSTM sweep, round 10.
// Grid (64 rowblk, 2 dir) = 128 blocks, 512 threads (8 waves, 2/EU pinned
// via launch_bounds -> 256 VGPR budget). Block owns rows [rb*32,+32) x all
// 256 h. Per step: out-copy of h(t-1) (overlapped), then passes q=0,1:
// acc init = zx (4 coalesced uint4), bfr kc-ring MFMA, next-pass zx issued
// after last bfr issue, epilogue writes h(t) to LDS only. One barrier/step.
__global__ __launch_bounds__(512, 2) void lstm_sweep6(
    const uint4* __restrict__ Zf, const uint4* __restrict__ rF,
    ushort* __restrict__ outbuf, int vert) {
  const int tid = threadIdx.x;
  const int lane = tid & 63, w = tid >> 6;
  const int l16 = lane & 15, kg = lane >> 4;
  const int rb = blockIdx.x, dir = (int)blockIdx.y;
  const int rowbase = rb << 5;

  __shared__ ushort hbuf[2][32 * 256];  // 2 x 16 KB, 16B-chunk XOR swizzle

  const uint4* rFd = rF + (size_t)dir * 32768;  // [64 tiles][8 kc][64 lanes]
  const uint4* zb = Zf + ((size_t)dir * 64 + rb) * 131072;

  float cst[2][2][4];  // [q][mt][r]
#pragma unroll
  for (int q = 0; q < 2; ++q)
#pragma unroll
    for (int mt = 0; mt < 2; ++mt)
#pragma unroll
      for (int r = 0; r < 4; ++r) cst[q][mt][r] = 0.f;

  unsigned int zA[4][4], zB[4][4];  // [chunk][gate]
  {
    const int seq0 = dir ? 31 : 0;
#pragma unroll
    for (int ch = 0; ch < 4; ++ch) {
      const uint4 v = zb[(size_t)((seq0 << 1) * 4 + ch) * 512 + tid];
      zA[ch][0] = v.x; zA[ch][1] = v.y; zA[ch][2] = v.z; zA[ch][3] = v.w;
    }
  }

  for (int t = 0; t < 32; ++t) {
    const int seq = dir ? (31 - t) : t;
    const ushort* hprev = hbuf[(t + 1) & 1];
    ushort* hnext = hbuf[t & 1];

    // ---- overlapped out-copy of h(t-1) (vectorized; race-free: epilogue
    // this step writes the OTHER ping buffer) ----
    if (t) {
      const int seqP = dir ? (32 - t) : (t - 1);
#pragma unroll
      for (int it = 0; it < 2; ++it) {
        const int c = tid + (it << 9);
        const int row = c >> 5, c4 = c & 31;
        const uint4 v = *(const uint4*)((const char*)hprev + row * 512 +
                                        ((c4 ^ (row & 7)) << 4));
        const int n = rowbase + row, b = n >> 5, sp = n & 31;
        const int X = vert ? seqP : sp, Y = vert ? sp : seqP;
        *(uint4*)&outbuf[(((size_t)(b * 32 + X) * 32 + Y) << 9) + (dir << 8) +
                         (c4 << 3)] = v;
      }
    }

#pragma unroll
    for (int q = 0; q < 2; ++q) {
      unsigned int(&zc)[4][4] = (q == 0) ? zA : zB;  // consumed this pass
      unsigned int(&zn)[4][4] = (q == 0) ? zB : zA;  // loaded for next pass

      // ---- acc init = zx ----
      f32x4 acc[2][4];
#pragma unroll
      for (int mt = 0; mt < 2; ++mt)
#pragma unroll
        for (int g = 0; g < 4; ++g) {
          acc[mt][g][0] = bf2f((ushort)(zc[2 * mt][g] & 0xffffu));
          acc[mt][g][1] = bf2f((ushort)(zc[2 * mt][g] >> 16));
          acc[mt][g][2] = bf2f((ushort)(zc[2 * mt + 1][g] & 0xffffu));
          acc[mt][g][3] = bf2f((ushort)(zc[2 * mt + 1][g] >> 16));
        }

      // ---- MFMA: acc += h(t-1) @ R, bfr kc-ring ----
      if (t) {
        uint4 bfr[2][4];
#pragma unroll
        for (int g = 0; g < 4; ++g)
          bfr[0][g] = rFd[(size_t)(((g << 4) + (w << 1) + q) << 3) * 64 + lane];
#pragma unroll
        for (int kc = 0; kc < 8; ++kc) {
          const int cur = kc & 1;
          if (kc < 7) {
#pragma unroll
            for (int g = 0; g < 4; ++g)
              bfr[cur ^ 1][g] =
                  rFd[((size_t)(((g << 4) + (w << 1) + q) << 3) + kc + 1) * 64 +
                      lane];
          }
          uint4 a[2];
#pragma unroll
          for (int mt = 0; mt < 2; ++mt) {
            const int row = (mt << 4) + l16;
            const int c4 = (kc << 2) + kg;
            a[mt] = *(const uint4*)((const char*)hprev + row * 512 +
                                    ((c4 ^ (row & 7)) << 4));
          }
#pragma unroll
          for (int mt = 0; mt < 2; ++mt)
#pragma unroll
            for (int g = 0; g < 4; ++g)
              acc[mt][g] = mfma16(__builtin_bit_cast(bf16x8, a[mt]),
                                  __builtin_bit_cast(bf16x8, bfr[cur][g]),
                                  acc[mt][g]);
        }
      }

      // ---- issue next-pass zx AFTER all bfr issues (no vmcnt inversion);
      // completes under the epilogue ----
      if (t < 31 || q == 0) {
        const int tn = q ? (t + 1) : t;
        const int qn = q ^ 1;
        const int seqn = dir ? (31 - tn) : tn;
#pragma unroll
        for (int ch = 0; ch < 4; ++ch) {
          const uint4 v = zb[(size_t)(((seqn << 1) + qn) * 4 + ch) * 512 + tid];
          zn[ch][0] = v.x; zn[ch][1] = v.y; zn[ch][2] = v.z; zn[ch][3] = v.w;
        }
      }

      // ---- gate epilogue -> h(t) into LDS only ----
      const int col = (w << 5) + (q << 4) + l16;
#pragma unroll
      for (int mt = 0; mt < 2; ++mt) {
#pragma unroll
        for (int r = 0; r < 4; ++r) {
          const float zi = acc[mt][0][r];
          const float zf = acc[mt][1][r];
          const float zg = acc[mt][2][r];
          const float zo = acc[mt][3][r];
          const float cn = sigm(zf) * cst[q][mt][r] + sigm(zi) * tanh_(zg);
          cst[q][mt][r] = cn;
          const float hv = sigm(zo) * tanh_(cn);
          const int row = (mt << 4) + (kg << 2) + r;
          *(ushort*)((char*)hnext + row * 512 +
                     (((col >> 3) ^ (row & 7)) << 4) + ((col & 7) << 1)) =
              f2bf(hv);
        }
      }
    }
    __syncthreads();  // h(t) complete; all h(t-1) reads done
  }

  // ---- final copy of h(31) ----
  {
    const int seqP = dir ? 0 : 31;
    const ushort* hl = hbuf[1];  // t=31 wrote hbuf[31&1] = hbuf[1]
#pragma unroll
    for (int it = 0; it < 2; ++it) {
      const int c = tid + (it << 9);
      const int row = c >> 5, c4 = c & 31;
      const uint4 v = *(const uint4*)((const char*)hl + row * 512 +
                                      ((c4 ^ (row & 7)) << 4));
      const int n = rowbase + row, b = n >> 5, sp = n & 31;
      const int X = vert ? seqP : sp, Y = vert ? sp : seqP;
      *(uint4*)&outbuf[(((size_t)(b * 32 + X) * 32 + Y) << 9) + (dir << 8) +
                       (c4 << 3)] = v;
    }
  }
}

// --------------------------------------------------------------------------
// C = A[M][512] @ BT[1024][512]^T + bias. 128x128 tile, BK=64,
// global_load_lds + XOR swizzle, XCD-aware remap, LDS-staged epilogue.
// EPI 0: N = 4 gates x 32 hcols (gate-split), writes fragment-major Zf
//        (uint4 across gates) -> perfectly coalesced, no cross-block lines.
// EPI 1: N contiguous, relu f32 store.
template <int EPI>
__global__ __launch_bounds__(256) void gemm_bt(
    const ushort* __restrict__ A, const ushort* __restrict__ BT,
    const float* __restrict__ bias, void* __restrict__ Cv) {
  const int tid = threadIdx.x;
  const int lane = tid & 63, wid = tid >> 6;
  const int l16 = lane & 15, kg = lane >> 4;
  const int wr = wid >> 1, wc = wid & 1;
  const int bid = blockIdx.x;
  const int xcd = bid & 7, lid = bid >> 3;
  const int m0 = ((xcd << 6) + (lid >> 3)) << 7;
  const int nblk = lid & 7;
  const int hc0 = nblk << 5;   // EPI0: 32 hcols x 4 gates
  const int n0 = nblk << 7;    // EPI1: 128 contiguous cols

  union SM {
    struct { uint4 A[128][8]; uint4 B[128][8]; } k;
    ushort eh[64][136];
    float ef[64][132];
  };
  __shared__ SM sm;

  f32x4 acc[4][4];
#pragma unroll
  for (int mt = 0; mt < 4; ++mt)
#pragma unroll
    for (int nt = 0; nt < 4; ++nt) acc[mt][nt] = (f32x4){0.f, 0.f, 0.f, 0.f};

  for (int k0 = 0; k0 < 512; k0 += 64) {
#pragma unroll
    for (int c = 0; c < 4; ++c) {
      const int cid = (wid << 8) + (c << 6) + lane;
      const int row = cid >> 3, ch = cid & 7;
      const int sch = ch ^ (row & 7);
      const int brow = (EPI == 0) ? (((row >> 5) << 8) + hc0 + (row & 31))
                                  : (n0 + row);
      load_lds16(A + (size_t)(m0 + row) * 512 + k0 + (sch << 3),
                 (uint4*)sm.k.A + (cid - lane));
      load_lds16(BT + (size_t)brow * 512 + k0 + (sch << 3),
                 (uint4*)sm.k.B + (cid - lane));
    }
    __syncthreads();
#pragma unroll
    for (int kk = 0; kk < 2; ++kk) {
      const int q = (kk << 2) + kg;
      bf16x8 a[4], b[4];
#pragma unroll
      for (int mt = 0; mt < 4; ++mt) {
        const int rr = (wr << 6) + (mt << 4) + l16;
        a[mt] = __builtin_bit_cast(bf16x8, sm.k.A[rr][q ^ (rr & 7)]);
      }
#pragma unroll
      for (int nt = 0; nt < 4; ++nt) {
        const int rr = (wc << 6) + (nt << 4) + l16;
        b[nt] = __builtin_bit_cast(bf16x8, sm.k.B[rr][q ^ (rr & 7)]);
      }
#pragma unroll
      for (int mt = 0; mt < 4; ++mt)
#pragma unroll
        for (int nt = 0; nt < 4; ++nt)
          acc[mt][nt] = mfma16(a[mt], b[nt], acc[mt][nt]);
    }
    __syncthreads();
  }

  float bn[4];
#pragma unroll
  for (int nt = 0; nt < 4; ++nt) {
    const int lcol = (wc << 6) + (nt << 4) + l16;
    const int gn = (EPI == 0) ? (((lcol >> 5) << 8) + hc0 + (lcol & 31))
                              : (n0 + lcol);
    bn[nt] = bias[gn];
  }

#pragma unroll
  for (int h = 0; h < 2; ++h) {
    __syncthreads();
    if (wr == h) {
#pragma unroll
      for (int nt = 0; nt < 4; ++nt) {
        const int col = (wc << 6) + (nt << 4) + l16;
#pragma unroll
        for (int mt = 0; mt < 4; ++mt) {
#pragma unroll
          for (int r = 0; r < 4; ++r) {
            const int rowl = (mt << 4) + (kg << 2) + r;
            const float v = acc[mt][nt][r] + bn[nt];
            if (EPI == 0)
              sm.eh[rowl][col] = f2bf(v);
            else
              sm.ef[rowl][col] = fmaxf(v, 0.f);
          }
        }
      }
    }
    __syncthreads();
    if (EPI == 0) {
      // half h = n-pair n2 = (m0>>6)+h, rows (2*n2, 2*n2+1) x 32 seq.
      uint4* Cz = (uint4*)Cv;
      const int n2 = (m0 >> 6) + h;
      const int rbz = n2 >> 4, n2l = n2 & 15;
      const int chunk = (((n2l >> 3)) << 1) + (n2l & 1);
      const int kgz = (n2l >> 1) & 3;
#pragma unroll
      for (int it = 0; it < 4; ++it) {
        const int e = tid + (it << 8);  // 0..1023
        const int seq = e >> 5, hl = e & 31;
        const int qv = hl >> 4, l16v = hl & 15;
        const int wz = (hc0 + hl) >> 5;
        const int tidz = (wz << 6) + (kgz << 4) + l16v;
        uint4 o;
        o.x = (unsigned int)sm.eh[seq][hl] |
              ((unsigned int)sm.eh[32 + seq][hl] << 16);
        o.y = (unsigned int)sm.eh[seq][32 + hl] |
              ((unsigned int)sm.eh[32 + seq][32 + hl] << 16);
        o.z = (unsigned int)sm.eh[seq][64 + hl] |
              ((unsigned int)sm.eh[32 + seq][64 + hl] << 16);
        o.w = (unsigned int)sm.eh[seq][96 + hl] |
              ((unsigned int)sm.eh[32 + seq][96 + hl] << 16);
        Cz[(size_t)rbz * 131072 + (size_t)(((seq << 1) + qv) * 4 + chunk) * 512 +
           tidz] = o;
      }
    } else {
      float* out = (float*)Cv;
#pragma unroll
      for (int q = 0; q < 8; ++q) {
        const int c = tid + (q << 8);
        const int row = c >> 5, co = (c & 31) << 2;
        typedef float f4v __attribute__((ext_vector_type(4)));
        const f4v v = *(const f4v*)&sm.ef[row][co];
        __builtin_nontemporal_store(
            v, (f4v*)(out + (size_t)(m0 + (h << 6) + row) * 1024 + n0 + co));
      }
    }
  }
}

}  // namespace

extern "C" void kernel_launch(void* const* d_in, const int* in_sizes, int n_in,
                              void* d_out, int out_size, void* d_ws, size_t ws_size,
                              hipStream_t stream) {
  (void)in_sizes; (void)n_in; (void)out_size; (void)ws_size;
  const float* x    = (const float*)d_in[0];
  const float* k_ud = (const float*)d_in[1];
  const float* r_ud = (const float*)d_in[2];
  const float* b_ud = (const float*)d_in[3];
  const float* k_du = (const float*)d_in[4];
  const float* r_du = (const float*)d_in[5];
  const float* b_du = (const float*)d_in[6];
  const float* k_lr = (const float*)d_in[7];
  const float* r_lr = (const float*)d_in[8];
  const float* b_lr = (const float*)d_in[9];
  const float* k_rl = (const float*)d_in[10];
  const float* r_rl = (const float*)d_in[11];
  const float* b_rl = (const float*)d_in[12];
  const float* Wd   = (const float*)d_in[13];
  const float* bd   = (const float*)d_in[14];

  ushort* W    = (ushort*)d_ws;
  ushort* Z    = W;                      // Zf: 2*64*131072 uint4 = 268 MB
  ushort* vbuf = Z + 134217728;          // [64][32][32][512]    33554432
  ushort* rF   = vbuf + 33554432;        // [4][64][8][64][8]     1048576
  ushort* kTh  = rF + 1048576;           // [2][1024][512]        1048576
  ushort* WdT  = kTh + 1048576;          // [1024][512]            524288
  uint4* Zf = (uint4*)Z;

  // ---- weight prep ----
  rfrag_kernel<<<128, 256, 0, stream>>>(r_ud, rF);
  rfrag_kernel<<<128, 256, 0, stream>>>(r_du, rF + 262144);
  rfrag_kernel<<<128, 256, 0, stream>>>(r_lr, rF + 524288);
  rfrag_kernel<<<128, 256, 0, stream>>>(r_rl, rF + 786432);
  transpose_bf16<<<2048, 256, 0, stream>>>(k_lr, kTh, 512);
  transpose_bf16<<<2048, 256, 0, stream>>>(k_rl, kTh + 524288, 512);
  transpose_bf16<<<2048, 256, 0, stream>>>(Wd, WdT, 512);

  // ---- vertical input projection (K=12) -> fragment-major Zf ----
  zxv3_kernel<<<dim3(16, 64, 2), 256, 0, stream>>>(x, k_ud, b_ud, k_du, b_du,
                                                   Zf);

  // ---- vertical sweep ----
  lstm_sweep6<<<dim3(64, 2), 512, 0, stream>>>(Zf, (const uint4*)rF, vbuf, 1);

  // ---- horizontal input projection: Zf = v @ k + b (per dir) ----
  gemm_bt<0><<<4096, 256, 0, stream>>>(vbuf, kTh, b_lr, (void*)Zf);
  gemm_bt<0><<<4096, 256, 0, stream>>>(vbuf, kTh + 524288, b_rl,
                                       (void*)(Zf + (size_t)64 * 131072));

  // ---- horizontal sweep (writes hfin over vbuf; reads only Zf) ----
  lstm_sweep6<<<dim3(64, 2), 512, 0, stream>>>(
      Zf, (const uint4*)(rF + 524288), vbuf, 0);

  // ---- dense + relu ----
  gemm_bt<1><<<4096, 256, 0, stream>>>(vbuf, WdT, bd, d_out);
}

// Round 11
// 901.177 us; speedup vs baseline: 3.4861x; 1.2332x over previous
//
#include <hip/hip_runtime.h>
#include <math.h>
#include <stddef.h>
#include <stdint.h>

// ---------------------------------------------------------------------------
// ReNet: patches -> vert bidir LSTM -> horiz bidir LSTM -> dense+relu
// B=64, I=J=32, D=12, HID=256, FC=1024.
// Round 11: 16-row sweep blocks -> grid 256 = 1 block/CU (whole chip busy;
// r10 ran on half). Per-CU VALU/MFMA halve; R-stream (512KB/step/CU from L2)
// is the new floor. Zf layout re-derived at 16-row granularity.
// ---------------------------------------------------------------------------

namespace {

typedef __bf16 bf16x8 __attribute__((ext_vector_type(8)));
typedef float f32x4 __attribute__((ext_vector_type(4)));
typedef __attribute__((address_space(1))) unsigned int as1_uint;
typedef __attribute__((address_space(3))) unsigned int as3_uint;

__device__ __forceinline__ float bf2f(ushort u) {
  return __builtin_bit_cast(float, (unsigned int)u << 16);
}
__device__ __forceinline__ ushort f2bf(float f) {
  unsigned int u = __builtin_bit_cast(unsigned int, f);
  u += 0x7fffu + ((u >> 16) & 1u);
  return (ushort)(u >> 16);
}
__device__ __forceinline__ unsigned int packbf(float a, float b) {
  return (unsigned int)f2bf(a) | ((unsigned int)f2bf(b) << 16);
}
__device__ __forceinline__ float sigm(float x) {
  return __fdividef(1.f, 1.f + __expf(-x));
}
__device__ __forceinline__ float tanh_(float x) {
  return 2.f * sigm(2.f * x) - 1.f;
}
__device__ __forceinline__ f32x4 mfma16(bf16x8 a, bf16x8 b, f32x4 c) {
  return __builtin_amdgcn_mfma_f32_16x16x32_bf16(a, b, c, 0, 0, 0);
}
__device__ __forceinline__ void load_lds16(const void* g, void* l) {
  __builtin_amdgcn_global_load_lds((const as1_uint*)g, (as3_uint*)l, 16, 0, 0);
}

// Zf fragment-major layout, per (dir, rb16) [rb16 = 16-row group, 0..127]:
// 65536 uint4. index = ((seq*2 + q)*2 + p)*512 + tidz ; components = gates.
// uint packs bf16 local rows (2*n2l, 2*n2l+1), n2l = kg*2+p (0..7),
// tidz = w*64 + kg*16 + l16 (== sweep tid), hcol = w*32 + q*16 + l16.
// dir stride = 128*65536 = 8388608 uint4.

// --------------------------------------------------------------------------
// transpose f32 [K][1024] -> bf16 [1024][K]  (for gemm B operands)
__global__ __launch_bounds__(256) void transpose_bf16(
    const float* __restrict__ in, ushort* __restrict__ out, int K) {
  const int idx = blockIdx.x * 256 + threadIdx.x;
  if (idx >= (K << 10)) return;
  const int n = idx / K, k = idx - n * K;
  out[idx] = f2bf(in[k * 1024 + n]);
}

// --------------------------------------------------------------------------
// Repack recurrent weights r [256][1024] f32 into MFMA B-fragment-major bf16
__global__ __launch_bounds__(256) void rfrag_kernel(
    const float* __restrict__ r, ushort* __restrict__ out) {
  const int id = blockIdx.x * 256 + threadIdx.x;  // 32768 ids
  const int lane = id & 63, kc = (id >> 6) & 7, tile = id >> 9;
  const int kbase = (kc << 5) + ((lane >> 4) << 3);
  const int col = (tile << 4) + (lane & 15);
  ushort tmp[8];
#pragma unroll
  for (int j = 0; j < 8; ++j) tmp[j] = f2bf(r[(size_t)(kbase + j) * 1024 + col]);
  *(uint4*)&out[(size_t)id << 3] = *(const uint4*)tmp;
}

// --------------------------------------------------------------------------
// Vertical input projection -> fragment-major Zf. Block (jp, b, dir), 256 thr;
// thread tid = hcol (0..255), computes all 4 gates for rows j0=2jp, j0+1.
__global__ __launch_bounds__(256) void zxv3_kernel(
    const float* __restrict__ x, const float* __restrict__ k0_,
    const float* __restrict__ b0_, const float* __restrict__ k1_,
    const float* __restrict__ b1_, uint4* __restrict__ Zf) {
  const int tid = threadIdx.x;
  const int jp = blockIdx.x, b = blockIdx.y, dir = blockIdx.z;
  const int j0 = jp << 1;
  const float* kw_ = dir ? k1_ : k0_;
  const float* bw_ = dir ? b1_ : b0_;
  __shared__ float ps[2][32][12];
  for (int e = tid; e < 2 * 32 * 12; e += 256) {
    const int jj = e / 384, rest = e - jj * 384;
    const int i = rest / 12, qq = rest - i * 12;
    const int pr = qq / 6, rem = qq - pr * 6;
    ps[jj][i][qq] =
        x[((size_t)((b * 64 + i * 2 + pr) * 64) + (j0 + jj) * 2 + rem / 3) * 3 + rem % 3];
  }
  __syncthreads();
  float kr[12][4], br[4];
#pragma unroll
  for (int qq = 0; qq < 12; ++qq)
#pragma unroll
    for (int g = 0; g < 4; ++g) kr[qq][g] = kw_[qq * 1024 + (g << 8) + tid];
#pragma unroll
  for (int g = 0; g < 4; ++g) br[g] = bw_[(g << 8) + tid];

  const int wv = tid >> 5, qv = (tid >> 4) & 1, l16v = tid & 15;
  const int rb16 = (b << 1) + (jp >> 3);
  const int n2l = jp & 7;
  const int kgz = n2l >> 1, pz = n2l & 1;
  const int tidz = (wv << 6) + (kgz << 4) + l16v;
  uint4* base = Zf + ((size_t)dir * 128 + rb16) * 65536;

  for (int i = 0; i < 32; ++i) {
    float z0[4], z1[4];
#pragma unroll
    for (int g = 0; g < 4; ++g) { z0[g] = br[g]; z1[g] = br[g]; }
#pragma unroll
    for (int qq = 0; qq < 12; ++qq) {
      const float p0 = ps[0][i][qq], p1 = ps[1][i][qq];
#pragma unroll
      for (int g = 0; g < 4; ++g) {
        z0[g] += p0 * kr[qq][g];
        z1[g] += p1 * kr[qq][g];
      }
    }
    uint4 o;
    o.x = packbf(z0[0], z1[0]);
    o.y = packbf(z0[1], z1[1]);
    o.z = packbf(z0[2], z1[2]);
    o.w = packbf(z0[3], z1[3]);
    base[(size_t)((((i << 1) + qv) << 1) + pz) * 512 + tidz] = o;
  }
}

// --------------------------------------------------------------------------
// Self-contained bidirectional LSTM sweep, round 11.
// Grid (128 rowblk, 2 dir) = 256 blocks (1/CU), 512 threads (8 waves).
// Block owns rows [rb*16,+16) x all 256 h; wave w owns h-cols [w*32,+32),
// passes q=0,1 (16 cols x 4 gates). acc init = zx (2 coalesced uint4);
// bfr kc-ring; next-pass zx after bfr issues; h in 2x8KB LDS; 1 barrier/step;
// h(t-1) out-copy overlapped at step start (1 uint4/thread).
__global__ __launch_bounds__(512) void lstm_sweep7(
    const uint4* __restrict__ Zf, const uint4* __restrict__ rF,
    ushort* __restrict__ outbuf, int vert) {
  const int tid = threadIdx.x;
  const int lane = tid & 63, w = tid >> 6;
  const int l16 = lane & 15, kg = lane >> 4;
  const int rb = blockIdx.x, dir = (int)blockIdx.y;
  const int rowbase = rb << 4;

  __shared__ ushort hbuf[2][16 * 256];  // 2 x 8 KB, 16B-chunk XOR swizzle

  const uint4* rFd = rF + (size_t)dir * 32768;  // [64 tiles][8 kc][64 lanes]
  const uint4* zb = Zf + ((size_t)dir * 128 + rb) * 65536;

  float cst[2][4];  // [q][r]
#pragma unroll
  for (int q = 0; q < 2; ++q)
#pragma unroll
    for (int r = 0; r < 4; ++r) cst[q][r] = 0.f;

  uint4 zA[2], zB[2];  // [p], components = gates
  {
    const int seq0 = dir ? 31 : 0;
    zA[0] = zb[(size_t)(seq0 << 2) * 512 + tid];
    zA[1] = zb[(size_t)((seq0 << 2) + 1) * 512 + tid];
  }

  for (int t = 0; t < 32; ++t) {
    const ushort* hprev = hbuf[(t + 1) & 1];
    ushort* hnext = hbuf[t & 1];

    // ---- overlapped out-copy of h(t-1) ----
    if (t) {
      const int seqP = dir ? (32 - t) : (t - 1);
      const int row = tid >> 5, c4 = tid & 31;
      const uint4 v = *(const uint4*)((const char*)hprev + row * 512 +
                                      ((c4 ^ (row & 7)) << 4));
      const int n = rowbase + row, b = n >> 5, sp = n & 31;
      const int X = vert ? seqP : sp, Y = vert ? sp : seqP;
      *(uint4*)&outbuf[(((size_t)(b * 32 + X) * 32 + Y) << 9) + (dir << 8) +
                       (c4 << 3)] = v;
    }

#pragma unroll
    for (int q = 0; q < 2; ++q) {
      uint4(&zc)[2] = (q == 0) ? zA : zB;  // consumed this pass
      uint4(&zn)[2] = (q == 0) ? zB : zA;  // loaded for next pass

      // ---- acc init = zx ----
      f32x4 acc[4];
#pragma unroll
      for (int g = 0; g < 4; ++g) {
        const unsigned int u0 = (g == 0) ? zc[0].x : (g == 1) ? zc[0].y
                                : (g == 2) ? zc[0].z : zc[0].w;
        const unsigned int u1 = (g == 0) ? zc[1].x : (g == 1) ? zc[1].y
                                : (g == 2) ? zc[1].z : zc[1].w;
        acc[g][0] = bf2f((ushort)(u0 & 0xffffu));
        acc[g][1] = bf2f((ushort)(u0 >> 16));
        acc[g][2] = bf2f((ushort)(u1 & 0xffffu));
        acc[g][3] = bf2f((ushort)(u1 >> 16));
      }

      // ---- MFMA: acc += h(t-1) @ R, bfr kc-ring ----
      if (t) {
        uint4 bfr[2][4];
#pragma unroll
        for (int g = 0; g < 4; ++g)
          bfr[0][g] = rFd[(size_t)(((g << 4) + (w << 1) + q) << 3) * 64 + lane];
#pragma unroll
        for (int kc = 0; kc < 8; ++kc) {
          const int cur = kc & 1;
          if (kc < 7) {
#pragma unroll
            for (int g = 0; g < 4; ++g)
              bfr[cur ^ 1][g] =
                  rFd[((size_t)(((g << 4) + (w << 1) + q) << 3) + kc + 1) * 64 +
                      lane];
          }
          const int c4 = (kc << 2) + kg;
          const uint4 a = *(const uint4*)((const char*)hprev + l16 * 512 +
                                          ((c4 ^ (l16 & 7)) << 4));
          const bf16x8 ab = __builtin_bit_cast(bf16x8, a);
#pragma unroll
          for (int g = 0; g < 4; ++g)
            acc[g] = mfma16(ab, __builtin_bit_cast(bf16x8, bfr[cur][g]), acc[g]);
        }
      }

      // ---- issue next-pass zx AFTER all bfr issues ----
      if (t < 31 || q == 0) {
        const int tn = q ? (t + 1) : t;
        const int qn = q ^ 1;
        const int seqn = dir ? (31 - tn) : tn;
        zn[0] = zb[(size_t)(((seqn << 1) + qn) << 1) * 512 + tid];
        zn[1] = zb[(size_t)((((seqn << 1) + qn) << 1) + 1) * 512 + tid];
      }

      // ---- gate epilogue -> h(t) into LDS only ----
      const int col = (w << 5) + (q << 4) + l16;
#pragma unroll
      for (int r = 0; r < 4; ++r) {
        const float zi = acc[0][r];
        const float zf = acc[1][r];
        const float zg = acc[2][r];
        const float zo = acc[3][r];
        const float cn = sigm(zf) * cst[q][r] + sigm(zi) * tanh_(zg);
        cst[q][r] = cn;
        const float hv = sigm(zo) * tanh_(cn);
        const int row = (kg << 2) + r;
        *(ushort*)((char*)hnext + row * 512 +
                   (((col >> 3) ^ (row & 7)) << 4) + ((col & 7) << 1)) =
            f2bf(hv);
      }
    }
    __syncthreads();  // h(t) complete; all h(t-1) reads done
  }

  // ---- final copy of h(31) ----
  {
    const int seqP = dir ? 0 : 31;
    const ushort* hl = hbuf[1];  // t=31 wrote hbuf[1]
    const int row = tid >> 5, c4 = tid & 31;
    const uint4 v = *(const uint4*)((const char*)hl + row * 512 +
                                    ((c4 ^ (row & 7)) << 4));
    const int n = rowbase + row, b = n >> 5, sp = n & 31;
    const int X = vert ? seqP : sp, Y = vert ? sp : seqP;
    *(uint4*)&outbuf[(((size_t)(b * 32 + X) * 32 + Y) << 9) + (dir << 8) +
                     (c4 << 3)] = v;
  }
}

// --------------------------------------------------------------------------
// C = A[M][512] @ BT[1024][512]^T + bias. 128x128 tile, BK=64,
// global_load_lds + XOR swizzle, XCD-aware remap, LDS-staged epilogue.
// EPI 0: N = 4 gates x 32 hcols (gate-split), writes fragment-major Zf.
// EPI 1: N contiguous, relu f32 store.
template <int EPI>
__global__ __launch_bounds__(256) void gemm_bt(
    const ushort* __restrict__ A, const ushort* __restrict__ BT,
    const float* __restrict__ bias, void* __restrict__ Cv) {
  const int tid = threadIdx.x;
  const int lane = tid & 63, wid = tid >> 6;
  const int l16 = lane & 15, kg = lane >> 4;
  const int wr = wid >> 1, wc = wid & 1;
  const int bid = blockIdx.x;
  const int xcd = bid & 7, lid = bid >> 3;
  const int m0 = ((xcd << 6) + (lid >> 3)) << 7;
  const int nblk = lid & 7;
  const int hc0 = nblk << 5;   // EPI0: 32 hcols x 4 gates
  const int n0 = nblk << 7;    // EPI1: 128 contiguous cols

  union SM {
    struct { uint4 A[128][8]; uint4 B[128][8]; } k;
    ushort eh[64][136];
    float ef[64][132];
  };
  __shared__ SM sm;

  f32x4 acc[4][4];
#pragma unroll
  for (int mt = 0; mt < 4; ++mt)
#pragma unroll
    for (int nt = 0; nt < 4; ++nt) acc[mt][nt] = (f32x4){0.f, 0.f, 0.f, 0.f};

  for (int k0 = 0; k0 < 512; k0 += 64) {
#pragma unroll
    for (int c = 0; c < 4; ++c) {
      const int cid = (wid << 8) + (c << 6) + lane;
      const int row = cid >> 3, ch = cid & 7;
      const int sch = ch ^ (row & 7);
      const int brow = (EPI == 0) ? (((row >> 5) << 8) + hc0 + (row & 31))
                                  : (n0 + row);
      load_lds16(A + (size_t)(m0 + row) * 512 + k0 + (sch << 3),
                 (uint4*)sm.k.A + (cid - lane));
      load_lds16(BT + (size_t)brow * 512 + k0 + (sch << 3),
                 (uint4*)sm.k.B + (cid - lane));
    }
    __syncthreads();
#pragma unroll
    for (int kk = 0; kk < 2; ++kk) {
      const int q = (kk << 2) + kg;
      bf16x8 a[4], b[4];
#pragma unroll
      for (int mt = 0; mt < 4; ++mt) {
        const int rr = (wr << 6) + (mt << 4) + l16;
        a[mt] = __builtin_bit_cast(bf16x8, sm.k.A[rr][q ^ (rr & 7)]);
      }
#pragma unroll
      for (int nt = 0; nt < 4; ++nt) {
        const int rr = (wc << 6) + (nt << 4) + l16;
        b[nt] = __builtin_bit_cast(bf16x8, sm.k.B[rr][q ^ (rr & 7)]);
      }
#pragma unroll
      for (int mt = 0; mt < 4; ++mt)
#pragma unroll
        for (int nt = 0; nt < 4; ++nt)
          acc[mt][nt] = mfma16(a[mt], b[nt], acc[mt][nt]);
    }
    __syncthreads();
  }

  float bn[4];
#pragma unroll
  for (int nt = 0; nt < 4; ++nt) {
    const int lcol = (wc << 6) + (nt << 4) + l16;
    const int gn = (EPI == 0) ? (((lcol >> 5) << 8) + hc0 + (lcol & 31))
                              : (n0 + lcol);
    bn[nt] = bias[gn];
  }

#pragma unroll
  for (int h = 0; h < 2; ++h) {
    __syncthreads();
    if (wr == h) {
#pragma unroll
      for (int nt = 0; nt < 4; ++nt) {
        const int col = (wc << 6) + (nt << 4) + l16;
#pragma unroll
        for (int mt = 0; mt < 4; ++mt) {
#pragma unroll
          for (int r = 0; r < 4; ++r) {
            const int rowl = (mt << 4) + (kg << 2) + r;
            const float v = acc[mt][nt][r] + bn[nt];
            if (EPI == 0)
              sm.eh[rowl][col] = f2bf(v);
            else
              sm.ef[rowl][col] = fmaxf(v, 0.f);
          }
        }
      }
    }
    __syncthreads();
    if (EPI == 0) {
      // half h covers rows n_a = 2*((m0>>6)+h), n_b = n_a+1, x 32 seq.
      uint4* Cz = (uint4*)Cv;
      const int n_a = ((m0 >> 6) + h) << 1;
      const int rbz = n_a >> 4;
      const int n2l = (n_a & 15) >> 1;
      const int kgz = n2l >> 1, pz = n2l & 1;
#pragma unroll
      for (int it = 0; it < 4; ++it) {
        const int e = tid + (it << 8);  // 0..1023
        const int seq = e >> 5, hl = e & 31;
        const int qv = hl >> 4, l16v = hl & 15;
        const int wz = (hc0 + hl) >> 5;
        const int tidz = (wz << 6) + (kgz << 4) + l16v;
        uint4 o;
        o.x = (unsigned int)sm.eh[seq][hl] |
              ((unsigned int)sm.eh[32 + seq][hl] << 16);
        o.y = (unsigned int)sm.eh[seq][32 + hl] |
              ((unsigned int)sm.eh[32 + seq][32 + hl] << 16);
        o.z = (unsigned int)sm.eh[seq][64 + hl] |
              ((unsigned int)sm.eh[32 + seq][64 + hl] << 16);
        o.w = (unsigned int)sm.eh[seq][96 + hl] |
              ((unsigned int)sm.eh[32 + seq][96 + hl] << 16);
        Cz[(size_t)rbz * 65536 + (size_t)((((seq << 1) + qv) << 1) + pz) * 512 +
           tidz] = o;
      }
    } else {
      float* out = (float*)Cv;
#pragma unroll
      for (int q = 0; q < 8; ++q) {
        const int c = tid + (q << 8);
        const int row = c >> 5, co = (c & 31) << 2;
        typedef float f4v __attribute__((ext_vector_type(4)));
        const f4v v = *(const f4v*)&sm.ef[row][co];
        __builtin_nontemporal_store(
            v, (f4v*)(out + (size_t)(m0 + (h << 6) + row) * 1024 + n0 + co));
      }
    }
  }
}

}  // namespace

extern "C" void kernel_launch(void* const* d_in, const int* in_sizes, int n_in,
                              void* d_out, int out_size, void* d_ws, size_t ws_size,
                              hipStream_t stream) {
  (void)in_sizes; (void)n_in; (void)out_size; (void)ws_size;
  const float* x    = (const float*)d_in[0];
  const float* k_ud = (const float*)d_in[1];
  const float* r_ud = (const float*)d_in[2];
  const float* b_ud = (const float*)d_in[3];
  const float* k_du = (const float*)d_in[4];
  const float* r_du = (const float*)d_in[5];
  const float* b_du = (const float*)d_in[6];
  const float* k_lr = (const float*)d_in[7];
  const float* r_lr = (const float*)d_in[8];
  const float* b_lr = (const float*)d_in[9];
  const float* k_rl = (const float*)d_in[10];
  const float* r_rl = (const float*)d_in[11];
  const float* b_rl = (const float*)d_in[12];
  const float* Wd   = (const float*)d_in[13];
  const float* bd   = (const float*)d_in[14];

  ushort* W    = (ushort*)d_ws;
  ushort* Z    = W;                      // Zf: 2*128*65536 uint4 = 268 MB
  ushort* vbuf = Z + 134217728;          // [64][32][32][512]    33554432
  ushort* rF   = vbuf + 33554432;        // [4][64][8][64][8]     1048576
  ushort* kTh  = rF + 1048576;           // [2][1024][512]        1048576
  ushort* WdT  = kTh + 1048576;          // [1024][512]            524288
  uint4* Zf = (uint4*)Z;

  // ---- weight prep ----
  rfrag_kernel<<<128, 256, 0, stream>>>(r_ud, rF);
  rfrag_kernel<<<128, 256, 0, stream>>>(r_du, rF + 262144);
  rfrag_kernel<<<128, 256, 0, stream>>>(r_lr, rF + 524288);
  rfrag_kernel<<<128, 256, 0, stream>>>(r_rl, rF + 786432);
  transpose_bf16<<<2048, 256, 0, stream>>>(k_lr, kTh, 512);
  transpose_bf16<<<2048, 256, 0, stream>>>(k_rl, kTh + 524288, 512);
  transpose_bf16<<<2048, 256, 0, stream>>>(Wd, WdT, 512);

  // ---- vertical input projection (K=12) -> fragment-major Zf ----
  zxv3_kernel<<<dim3(16, 64, 2), 256, 0, stream>>>(x, k_ud, b_ud, k_du, b_du,
                                                   Zf);

  // ---- vertical sweep ----
  lstm_sweep7<<<dim3(128, 2), 512, 0, stream>>>(Zf, (const uint4*)rF, vbuf, 1);

  // ---- horizontal input projection: Zf = v @ k + b (per dir) ----
  gemm_bt<0><<<4096, 256, 0, stream>>>(vbuf, kTh, b_lr, (void*)Zf);
  gemm_bt<0><<<4096, 256, 0, stream>>>(vbuf, kTh + 524288, b_rl,
                                       (void*)(Zf + (size_t)128 * 65536));

  // ---- horizontal sweep (writes hfin over vbuf; reads only Zf) ----
  lstm_sweep7<<<dim3(128, 2), 512, 0, stream>>>(
      Zf, (const uint4*)(rF + 524288), vbuf, 0);

  // ---- dense + relu ----
  gemm_bt<1><<<4096, 256, 0, stream>>>(vbuf, WdT, bd, d_out);
}